// Round 4
// baseline (230.296 us; speedup 1.0000x reference)
//
#include <hip/hip_runtime.h>
#include <hip/hip_fp16.h>
#include <stdint.h>

#define M_TOTAL 16384
#define N_TOTAL 572
#define N_PAD   640
#define K_TOTAL 1024
#define D_TOTAL 1024

typedef _Float16 f16;
typedef __attribute__((ext_vector_type(8))) _Float16 f16x8;
typedef __attribute__((ext_vector_type(4))) float f32x4;

// ---------------------------------------------------------------------------
// convert_w: W1 f32 [K,572] -> transposed hi/lo f16 planes [640,K] (d_ws),
// rows 572..639 zero-filled so the GEMM needs no B masks.
// ---------------------------------------------------------------------------
__global__ __launch_bounds__(256) void convert_w(const float* __restrict__ W,
                                                 f16* __restrict__ thi,
                                                 f16* __restrict__ tlo) {
  __shared__ float tile[32][33];
  const int n0 = blockIdx.x * 32, k0 = blockIdx.y * 32;
  const int tx = threadIdx.x & 31, ty = threadIdx.x >> 5;  // 32 x 8
#pragma unroll
  for (int s = 0; s < 32; s += 8) {
    const int k = k0 + ty + s, n = n0 + tx;
    tile[ty + s][tx] = (n < N_TOTAL) ? W[(size_t)k * N_TOTAL + n] : 0.0f;
  }
  __syncthreads();
#pragma unroll
  for (int s = 0; s < 32; s += 8) {
    const int n = n0 + ty + s, k = k0 + tx;
    const float x = tile[tx][ty + s];
    const f16 h = (f16)x;
    thi[(size_t)n * K_TOTAL + k] = h;
    tlo[(size_t)n * K_TOTAL + k] = (f16)(x - (float)h);
  }
}

// ---------------------------------------------------------------------------
// gemm_direct: pre = core @ W1 + b1 via 3-pass split-f16 MFMA, NO LDS.
// 4 waves/block, each wave owns an independent 64x64 output tile.
// A fragments: global f32 -> in-register hi/lo f16 (16 rows x 128B coalesced).
// B fragments: f16x8 direct from the 2.6MB L2-resident transposed planes.
// No __syncthreads in the K-loop.
// ---------------------------------------------------------------------------
__global__ __launch_bounds__(256) void gemm_direct(
    const float* __restrict__ A,
    const f16* __restrict__ bHi, const f16* __restrict__ bLo,
    const float* __restrict__ b1, float* __restrict__ C) {
  const int t = threadIdx.x;
  const int lane = t & 63, wid = t >> 6;
  const int wm = wid >> 1, wn = wid & 1;  // 2x2 waves, tile 64x64 each

  // bijective XCD swizzle: 640 = 8 XCDs x 80 blocks; the 5 n-siblings of an
  // A-panel are consecutive -> concurrent on one XCD -> A read ~once from HBM.
  const int bid = blockIdx.x;
  const int wg = (bid & 7) * 80 + (bid >> 3);
  const int nb = wg % 5, mb = wg / 5;
  const int m0 = mb * 128 + wm * 64;
  const int n0 = nb * 128 + wn * 64;

  const int fr = lane & 15, fq = lane >> 4;

  const float* aRow = A + (size_t)(m0 + fr) * K_TOTAL + fq * 8;
  const f16* bhRow = bHi + (size_t)(n0 + fr) * K_TOTAL + fq * 8;
  const f16* blRow = bLo + (size_t)(n0 + fr) * K_TOTAL + fq * 8;

  f32x4 acc[4][4] = {};

  for (int k0 = 0; k0 < K_TOTAL; k0 += 32) {
    // A fragments: load f32, split to hi/lo f16 in-register
    f16x8 ah[4], al[4];
#pragma unroll
    for (int mi = 0; mi < 4; ++mi) {
      const float* p = aRow + (size_t)mi * 16 * K_TOTAL + k0;
      const float4 v0 = *reinterpret_cast<const float4*>(p);
      const float4 v1 = *reinterpret_cast<const float4*>(p + 4);
      const float x[8] = {v0.x, v0.y, v0.z, v0.w, v1.x, v1.y, v1.z, v1.w};
#pragma unroll
      for (int j = 0; j < 8; ++j) {
        const f16 h = (f16)x[j];
        ah[mi][j] = h;
        al[mi][j] = (f16)(x[j] - (float)h);
      }
    }
#pragma unroll
    for (int ni = 0; ni < 4; ++ni) {
      const f16x8 bh = *reinterpret_cast<const f16x8*>(bhRow + (size_t)ni * 16 * K_TOTAL + k0);
      const f16x8 bl = *reinterpret_cast<const f16x8*>(blRow + (size_t)ni * 16 * K_TOTAL + k0);
#pragma unroll
      for (int mi = 0; mi < 4; ++mi) {
        acc[mi][ni] = __builtin_amdgcn_mfma_f32_16x16x32_f16(ah[mi], bh, acc[mi][ni], 0, 0, 0);
        acc[mi][ni] = __builtin_amdgcn_mfma_f32_16x16x32_f16(ah[mi], bl, acc[mi][ni], 0, 0, 0);
        acc[mi][ni] = __builtin_amdgcn_mfma_f32_16x16x32_f16(al[mi], bh, acc[mi][ni], 0, 0, 0);
      }
    }
  }

  // epilogue: + b1, masked store (C/D layout: col=lane&15, row=(lane>>4)*4+r)
#pragma unroll
  for (int ni = 0; ni < 4; ++ni) {
    const int n = n0 + ni * 16 + fr;
    if (n >= N_TOTAL) continue;
    const float bb = b1[n];
#pragma unroll
    for (int mi = 0; mi < 4; ++mi) {
      const int mbase = m0 + mi * 16 + fq * 4;
#pragma unroll
      for (int r = 0; r < 4; ++r)
        C[(size_t)(mbase + r) * N_TOTAL + n] = acc[mi][ni][r] + bb;
    }
  }
}

// ---------------------------------------------------------------------------
// Fallback f32 vector GEMM (only if ws_size is too small for W1 planes)
// ---------------------------------------------------------------------------
__global__ __launch_bounds__(256) void gemm_pre(const float* __restrict__ A,
                                                const float* __restrict__ W,
                                                const float* __restrict__ b1,
                                                float* __restrict__ C) {
  __shared__ float As_[16][64];
  __shared__ float Bs_[16][64];
  const int t = threadIdx.x;
  const int tx = t & 15, ty = t >> 4;
  const int m0 = blockIdx.y * 64;
  const int n0 = blockIdx.x * 64;
  const int ar = t >> 2, ac4 = (t & 3) << 2;
  const int bk = t >> 4, bn4 = (t & 15) << 2;
  float acc[4][4] = {};
  for (int k0 = 0; k0 < K_TOTAL; k0 += 16) {
    float4 av = *reinterpret_cast<const float4*>(A + (size_t)(m0 + ar) * K_TOTAL + k0 + ac4);
    As_[ac4 + 0][ar] = av.x;
    As_[ac4 + 1][ar] = av.y;
    As_[ac4 + 2][ar] = av.z;
    As_[ac4 + 3][ar] = av.w;
    float4 bv = make_float4(0.f, 0.f, 0.f, 0.f);
    const int gn = n0 + bn4;
    if (gn < N_TOTAL)
      bv = *reinterpret_cast<const float4*>(W + (size_t)(k0 + bk) * N_TOTAL + gn);
    *reinterpret_cast<float4*>(&Bs_[bk][bn4]) = bv;
    __syncthreads();
#pragma unroll
    for (int kk = 0; kk < 16; ++kk) {
      float4 a = *reinterpret_cast<const float4*>(&As_[kk][ty << 2]);
      float4 b = *reinterpret_cast<const float4*>(&Bs_[kk][tx << 2]);
      const float aa[4] = {a.x, a.y, a.z, a.w};
      const float bb[4] = {b.x, b.y, b.z, b.w};
#pragma unroll
      for (int i = 0; i < 4; ++i)
#pragma unroll
        for (int j = 0; j < 4; ++j)
          acc[i][j] = fmaf(aa[i], bb[j], acc[i][j]);
    }
    __syncthreads();
  }
#pragma unroll
  for (int j = 0; j < 4; ++j) {
    const int n = n0 + (tx << 2) + j;
    if (n < N_TOTAL) {
      const float bj = b1[n];
#pragma unroll
      for (int i = 0; i < 4; ++i) {
        const int m = m0 + (ty << 2) + i;
        C[(size_t)m * N_TOTAL + n] = acc[i][j] + bj;
      }
    }
  }
}

// ---------------------------------------------------------------------------
// JAX threefry2x32, key(42) -> (0,42); partitionable random_bits (32-bit)
// ---------------------------------------------------------------------------
__device__ __forceinline__ float jax_gumbel(uint32_t idx) {
  const uint32_t ks0 = 0u;
  const uint32_t ks1 = 42u;
  const uint32_t ks2 = 0x1BD11BDAu ^ ks0 ^ ks1;
  uint32_t x0 = ks0;
  uint32_t x1 = idx + ks1;
#define TF_ROUND(r) { x0 += x1; x1 = (x1 << (r)) | (x1 >> (32 - (r))); x1 ^= x0; }
  TF_ROUND(13) TF_ROUND(15) TF_ROUND(26) TF_ROUND(6)
  x0 += ks1; x1 += ks2 + 1u;
  TF_ROUND(17) TF_ROUND(29) TF_ROUND(16) TF_ROUND(24)
  x0 += ks2; x1 += ks0 + 2u;
  TF_ROUND(13) TF_ROUND(15) TF_ROUND(26) TF_ROUND(6)
  x0 += ks0; x1 += ks1 + 3u;
  TF_ROUND(17) TF_ROUND(29) TF_ROUND(16) TF_ROUND(24)
  x0 += ks1; x1 += ks2 + 4u;
  TF_ROUND(13) TF_ROUND(15) TF_ROUND(26) TF_ROUND(6)
  x0 += ks2; x1 += ks0 + 5u;
#undef TF_ROUND
  const uint32_t bits = x0 ^ x1;
  union { uint32_t u; float f; } cvt;
  cvt.u = (bits >> 9) | 0x3F800000u;
  const float fl = cvt.f - 1.0f;
  const float TINY = 1.1754943508222875e-38f;
  const float u = fmaxf(TINY, fl * 1.0f + TINY);
  return -logf(-logf(u));
}

// ---------------------------------------------------------------------------
// head_kernel: per row -- softmax (in-place), gumbel argmax, gather+relu+add
// ---------------------------------------------------------------------------
__global__ __launch_bounds__(256) void head_kernel(
    float* __restrict__ pre_probs,
    const float* __restrict__ core,
    const float* __restrict__ W2,
    const float* __restrict__ b2,
    float* __restrict__ out1) {
  const int row = blockIdx.x;
  const int t = threadIdx.x;
  const int lane = t & 63, wid = t >> 6;

  __shared__ float s_max[4];
  __shared__ float s_sum[4];
  __shared__ float s_av[4];
  __shared__ int   s_ai[4];

  float* xrow = pre_probs + (size_t)row * N_TOTAL;
  const int c0 = t, c1 = t + 256, c2 = t + 512;
  const bool v1 = (c1 < N_TOTAL), v2 = (c2 < N_TOTAL);
  const float NEG_INF = -__builtin_inff();

  const float x0v = xrow[c0];
  const float x1v = v1 ? xrow[c1] : NEG_INF;
  const float x2v = v2 ? xrow[c2] : NEG_INF;

  float vmax = fmaxf(x0v, fmaxf(x1v, x2v));
#pragma unroll
  for (int off = 32; off > 0; off >>= 1)
    vmax = fmaxf(vmax, __shfl_xor(vmax, off, 64));
  if (lane == 0) s_max[wid] = vmax;
  __syncthreads();
  const float m = fmaxf(fmaxf(s_max[0], s_max[1]), fmaxf(s_max[2], s_max[3]));

  const float e0 = expf(x0v - m);
  const float e1 = v1 ? expf(x1v - m) : 0.0f;
  const float e2 = v2 ? expf(x2v - m) : 0.0f;
  float vsum = e0 + e1 + e2;
#pragma unroll
  for (int off = 32; off > 0; off >>= 1)
    vsum += __shfl_xor(vsum, off, 64);
  if (lane == 0) s_sum[wid] = vsum;
  __syncthreads();
  const float sum = (s_sum[0] + s_sum[1]) + (s_sum[2] + s_sum[3]);

  const float lse = logf(sum);
  xrow[c0] = e0 / sum;
  if (v1) xrow[c1] = e1 / sum;
  if (v2) xrow[c2] = e2 / sum;

  const uint32_t base = (uint32_t)row * (uint32_t)N_TOTAL;
  float bv = jax_gumbel(base + c0) + ((x0v - m) - lse);
  int bi = c0;
  if (v1) {
    const float s1 = jax_gumbel(base + c1) + ((x1v - m) - lse);
    if (s1 > bv) { bv = s1; bi = c1; }
  }
  if (v2) {
    const float s2 = jax_gumbel(base + c2) + ((x2v - m) - lse);
    if (s2 > bv) { bv = s2; bi = c2; }
  }
#pragma unroll
  for (int off = 32; off > 0; off >>= 1) {
    const float ov = __shfl_xor(bv, off, 64);
    const int oi = __shfl_xor(bi, off, 64);
    if (ov > bv || (ov == bv && oi < bi)) { bv = ov; bi = oi; }
  }
  if (lane == 0) { s_av[wid] = bv; s_ai[wid] = bi; }
  __syncthreads();
  float best = s_av[0]; int action = s_ai[0];
#pragma unroll
  for (int w = 1; w < 4; ++w) {
    if (s_av[w] > best || (s_av[w] == best && s_ai[w] < action)) {
      best = s_av[w]; action = s_ai[w];
    }
  }

  const float* __restrict__ w2row = W2 + (size_t)action * D_TOTAL;
  const float* __restrict__ crow = core + (size_t)row * D_TOTAL;
  float* __restrict__ orow = out1 + (size_t)row * D_TOTAL;
#pragma unroll
  for (int d = t; d < D_TOTAL; d += 256) {
    const float h = w2row[d] + b2[d];
    orow[d] = fmaxf(h, 0.0f) + crow[d];
  }
}

// ---------------------------------------------------------------------------
extern "C" void kernel_launch(void* const* d_in, const int* in_sizes, int n_in,
                              void* d_out, int out_size, void* d_ws, size_t ws_size,
                              hipStream_t stream) {
  const float* core = (const float*)d_in[0];  // [16384,1024]
  const float* W1   = (const float*)d_in[1];  // [1024,572]
  const float* b1   = (const float*)d_in[2];  // [572]
  const float* W2   = (const float*)d_in[3];  // [572,1024]
  const float* b2   = (const float*)d_in[4];  // [1024]

  float* probs = (float*)d_out;                              // [16384,572]
  float* out1  = (float*)d_out + (size_t)M_TOTAL * N_TOTAL;  // [16384,1024]

  const size_t wneed = (size_t)2 * N_PAD * K_TOTAL * sizeof(f16);  // 2.6 MB
  if (ws_size >= wneed) {
    f16* wHi = (f16*)d_ws;
    f16* wLo = wHi + (size_t)N_PAD * K_TOTAL;
    convert_w<<<dim3(N_PAD / 32, K_TOTAL / 32), 256, 0, stream>>>(W1, wHi, wLo);
    gemm_direct<<<(M_TOTAL / 128) * (N_PAD / 128), 256, 0, stream>>>(core, wHi, wLo, b1, probs);
  } else {
    gemm_pre<<<dim3((N_TOTAL + 63) / 64, M_TOTAL / 64), 256, 0, stream>>>(core, W1, b1, probs);
  }

  head_kernel<<<M_TOTAL, 256, 0, stream>>>(probs, core, W2, b2, out1);
}

// Round 5
// 137.310 us; speedup vs baseline: 1.6772x; 1.6772x over previous
//
#include <hip/hip_runtime.h>
#include <hip/hip_fp16.h>
#include <stdint.h>

#define M_TOTAL 16384
#define N_TOTAL 572
#define N_PAD   640
#define K_TOTAL 1024
#define D_TOTAL 1024

typedef _Float16 f16;
typedef __attribute__((ext_vector_type(8))) _Float16 f16x8;
typedef __attribute__((ext_vector_type(4))) float f32x4;

// ---------------------------------------------------------------------------
// convert_w: W1 f32 [K,572] -> transposed hi/lo f16 planes [640,K] (d_ws),
// rows 572..639 zero-filled so the GEMM needs no B masks.
// ---------------------------------------------------------------------------
__global__ __launch_bounds__(256) void convert_w(const float* __restrict__ W,
                                                 f16* __restrict__ thi,
                                                 f16* __restrict__ tlo) {
  __shared__ float tile[32][33];
  const int n0 = blockIdx.x * 32, k0 = blockIdx.y * 32;
  const int tx = threadIdx.x & 31, ty = threadIdx.x >> 5;  // 32 x 8
#pragma unroll
  for (int s = 0; s < 32; s += 8) {
    const int k = k0 + ty + s, n = n0 + tx;
    tile[ty + s][tx] = (n < N_TOTAL) ? W[(size_t)k * N_TOTAL + n] : 0.0f;
  }
  __syncthreads();
#pragma unroll
  for (int s = 0; s < 32; s += 8) {
    const int n = n0 + ty + s, k = k0 + tx;
    const float x = tile[tx][ty + s];
    const f16 h = (f16)x;
    thi[(size_t)n * K_TOTAL + k] = h;
    tlo[(size_t)n * K_TOTAL + k] = (f16)(x - (float)h);
  }
}

// ---------------------------------------------------------------------------
// gemm_frag: pre = core @ W1 + b1 via 3-pass split-f16 MFMA.
// Block 256 thr = 4 waves (2x2), tile 64x128, wave tile 32x64, acc[2][4]
// (FULL tile coverage). BK=32, single LDS buffer + register prefetch.
// LDS is FRAGMENT-ORDERED: granule = f16x8 (16B), layout [plane][T][fq][fr]
// so each wave fragment read is a contiguous 1KB ds_read_b128 (addr =
// base + lane*16) -> zero bank conflicts; staging writes are <=2 lanes/bank.
// Grid 1280 blocks = 8 XCDs x 160, bijective swizzle keeps the 5 n-siblings
// of each A panel on one XCD for L2 reuse.
// ---------------------------------------------------------------------------
#define BMF 64
#define BNF 128

__global__ __launch_bounds__(256, 4) void gemm_frag(
    const float* __restrict__ A,
    const f16* __restrict__ bHi, const f16* __restrict__ bLo,
    const float* __restrict__ b1, float* __restrict__ C) {
  __shared__ f16x8 Ag[2][4][4][16];  // [plane][rowtile][fq][fr]  8 KB
  __shared__ f16x8 Bg[2][8][4][16];  // [plane][coltile][fq][fr] 16 KB

  const int t = threadIdx.x;
  const int lane = t & 63, wid = t >> 6;
  const int wm = wid >> 1, wn = wid & 1;  // 2x2 waves, wave tile 32x64
  const int fr = lane & 15, fq = lane >> 4;

  // bijective XCD swizzle: 1280 = 8 * 160
  const int bid = blockIdx.x;
  const int wg = (bid & 7) * 160 + (bid >> 3);
  const int nb = wg % 5, mb = wg / 5;
  const int m0 = mb * BMF, n0 = nb * BNF;

  // staging assignments: A = 64 rows x 4 k-segs, B = 128 cols x 2 k-seg pairs
  const int arow = t >> 2, afq = t & 3;
  const int bcol = t >> 1, bhf = t & 1;
  const float* aP = A + (size_t)(m0 + arow) * K_TOTAL + afq * 8;
  const f16* bhP = bHi + (size_t)(n0 + bcol) * K_TOTAL + bhf * 16;
  const f16* blP = bLo + (size_t)(n0 + bcol) * K_TOTAL + bhf * 16;

  float4 pa0, pa1;
  f16x8 pbh[2], pbl[2];

  auto LOADK = [&](int k0) {
    pa0 = *reinterpret_cast<const float4*>(aP + k0);
    pa1 = *reinterpret_cast<const float4*>(aP + k0 + 4);
    pbh[0] = *reinterpret_cast<const f16x8*>(bhP + k0);
    pbh[1] = *reinterpret_cast<const f16x8*>(bhP + k0 + 8);
    pbl[0] = *reinterpret_cast<const f16x8*>(blP + k0);
    pbl[1] = *reinterpret_cast<const f16x8*>(blP + k0 + 8);
  };
  auto WRITELDS = [&]() {
    const float x[8] = {pa0.x, pa0.y, pa0.z, pa0.w, pa1.x, pa1.y, pa1.z, pa1.w};
    f16x8 gh, gl;
#pragma unroll
    for (int j = 0; j < 8; ++j) {
      const f16 h = (f16)x[j];
      gh[j] = h;
      gl[j] = (f16)(x[j] - (float)h);
    }
    Ag[0][arow >> 4][afq][arow & 15] = gh;
    Ag[1][arow >> 4][afq][arow & 15] = gl;
    Bg[0][bcol >> 4][bhf * 2 + 0][bcol & 15] = pbh[0];
    Bg[0][bcol >> 4][bhf * 2 + 1][bcol & 15] = pbh[1];
    Bg[1][bcol >> 4][bhf * 2 + 0][bcol & 15] = pbl[0];
    Bg[1][bcol >> 4][bhf * 2 + 1][bcol & 15] = pbl[1];
  };

  f32x4 acc[2][4] = {};

  LOADK(0);
  for (int k0 = 0; k0 < K_TOTAL; k0 += 32) {
    __syncthreads();  // previous compute's LDS reads done
    WRITELDS();
    if (k0 + 32 < K_TOTAL) LOADK(k0 + 32);  // next tile in flight over compute
    __syncthreads();

    f16x8 ah[2], al[2];
#pragma unroll
    for (int mi = 0; mi < 2; ++mi) {
      ah[mi] = Ag[0][wm * 2 + mi][fq][fr];
      al[mi] = Ag[1][wm * 2 + mi][fq][fr];
    }
#pragma unroll
    for (int ni = 0; ni < 4; ++ni) {
      const f16x8 bh = Bg[0][wn * 4 + ni][fq][fr];
      const f16x8 bl = Bg[1][wn * 4 + ni][fq][fr];
#pragma unroll
      for (int mi = 0; mi < 2; ++mi) {
        acc[mi][ni] = __builtin_amdgcn_mfma_f32_16x16x32_f16(ah[mi], bh, acc[mi][ni], 0, 0, 0);
        acc[mi][ni] = __builtin_amdgcn_mfma_f32_16x16x32_f16(ah[mi], bl, acc[mi][ni], 0, 0, 0);
        acc[mi][ni] = __builtin_amdgcn_mfma_f32_16x16x32_f16(al[mi], bh, acc[mi][ni], 0, 0, 0);
      }
    }
  }

  // epilogue: + b1, masked store (C/D layout: col=lane&15, row=(lane>>4)*4+r)
#pragma unroll
  for (int ni = 0; ni < 4; ++ni) {
    const int n = n0 + wn * 64 + ni * 16 + fr;
    if (n >= N_TOTAL) continue;
    const float bb = b1[n];
#pragma unroll
    for (int mi = 0; mi < 2; ++mi) {
      const int mbase = m0 + wm * 32 + mi * 16 + fq * 4;
#pragma unroll
      for (int r = 0; r < 4; ++r)
        C[(size_t)(mbase + r) * N_TOTAL + n] = acc[mi][ni][r] + bb;
    }
  }
}

// ---------------------------------------------------------------------------
// Fallback f32 vector GEMM (only if ws_size is too small for W1 planes)
// ---------------------------------------------------------------------------
__global__ __launch_bounds__(256) void gemm_pre(const float* __restrict__ A,
                                                const float* __restrict__ W,
                                                const float* __restrict__ b1,
                                                float* __restrict__ C) {
  __shared__ float As_[16][64];
  __shared__ float Bs_[16][64];
  const int t = threadIdx.x;
  const int tx = t & 15, ty = t >> 4;
  const int m0 = blockIdx.y * 64;
  const int n0 = blockIdx.x * 64;
  const int ar = t >> 2, ac4 = (t & 3) << 2;
  const int bk = t >> 4, bn4 = (t & 15) << 2;
  float acc[4][4] = {};
  for (int k0 = 0; k0 < K_TOTAL; k0 += 16) {
    float4 av = *reinterpret_cast<const float4*>(A + (size_t)(m0 + ar) * K_TOTAL + k0 + ac4);
    As_[ac4 + 0][ar] = av.x;
    As_[ac4 + 1][ar] = av.y;
    As_[ac4 + 2][ar] = av.z;
    As_[ac4 + 3][ar] = av.w;
    float4 bv = make_float4(0.f, 0.f, 0.f, 0.f);
    const int gn = n0 + bn4;
    if (gn < N_TOTAL)
      bv = *reinterpret_cast<const float4*>(W + (size_t)(k0 + bk) * N_TOTAL + gn);
    *reinterpret_cast<float4*>(&Bs_[bk][bn4]) = bv;
    __syncthreads();
#pragma unroll
    for (int kk = 0; kk < 16; ++kk) {
      float4 a = *reinterpret_cast<const float4*>(&As_[kk][ty << 2]);
      float4 b = *reinterpret_cast<const float4*>(&Bs_[kk][tx << 2]);
      const float aa[4] = {a.x, a.y, a.z, a.w};
      const float bb[4] = {b.x, b.y, b.z, b.w};
#pragma unroll
      for (int i = 0; i < 4; ++i)
#pragma unroll
        for (int j = 0; j < 4; ++j)
          acc[i][j] = fmaf(aa[i], bb[j], acc[i][j]);
    }
    __syncthreads();
  }
#pragma unroll
  for (int j = 0; j < 4; ++j) {
    const int n = n0 + (tx << 2) + j;
    if (n < N_TOTAL) {
      const float bj = b1[n];
#pragma unroll
      for (int i = 0; i < 4; ++i) {
        const int m = m0 + (ty << 2) + i;
        C[(size_t)m * N_TOTAL + n] = acc[i][j] + bj;
      }
    }
  }
}

// ---------------------------------------------------------------------------
// JAX threefry2x32, key(42) -> (0,42); partitionable random_bits (32-bit)
// ---------------------------------------------------------------------------
__device__ __forceinline__ float jax_gumbel(uint32_t idx) {
  const uint32_t ks0 = 0u;
  const uint32_t ks1 = 42u;
  const uint32_t ks2 = 0x1BD11BDAu ^ ks0 ^ ks1;
  uint32_t x0 = ks0;
  uint32_t x1 = idx + ks1;
#define TF_ROUND(r) { x0 += x1; x1 = (x1 << (r)) | (x1 >> (32 - (r))); x1 ^= x0; }
  TF_ROUND(13) TF_ROUND(15) TF_ROUND(26) TF_ROUND(6)
  x0 += ks1; x1 += ks2 + 1u;
  TF_ROUND(17) TF_ROUND(29) TF_ROUND(16) TF_ROUND(24)
  x0 += ks2; x1 += ks0 + 2u;
  TF_ROUND(13) TF_ROUND(15) TF_ROUND(26) TF_ROUND(6)
  x0 += ks0; x1 += ks1 + 3u;
  TF_ROUND(17) TF_ROUND(29) TF_ROUND(16) TF_ROUND(24)
  x0 += ks1; x1 += ks2 + 4u;
  TF_ROUND(13) TF_ROUND(15) TF_ROUND(26) TF_ROUND(6)
  x0 += ks2; x1 += ks0 + 5u;
#undef TF_ROUND
  const uint32_t bits = x0 ^ x1;
  union { uint32_t u; float f; } cvt;
  cvt.u = (bits >> 9) | 0x3F800000u;
  const float fl = cvt.f - 1.0f;
  const float TINY = 1.1754943508222875e-38f;
  const float u = fmaxf(TINY, fl * 1.0f + TINY);
  return -logf(-logf(u));
}

// ---------------------------------------------------------------------------
// head_kernel: per row -- softmax (in-place), gumbel argmax, gather+relu+add
// ---------------------------------------------------------------------------
__global__ __launch_bounds__(256) void head_kernel(
    float* __restrict__ pre_probs,
    const float* __restrict__ core,
    const float* __restrict__ W2,
    const float* __restrict__ b2,
    float* __restrict__ out1) {
  const int row = blockIdx.x;
  const int t = threadIdx.x;
  const int lane = t & 63, wid = t >> 6;

  __shared__ float s_max[4];
  __shared__ float s_sum[4];
  __shared__ float s_av[4];
  __shared__ int   s_ai[4];

  float* xrow = pre_probs + (size_t)row * N_TOTAL;
  const int c0 = t, c1 = t + 256, c2 = t + 512;
  const bool v1 = (c1 < N_TOTAL), v2 = (c2 < N_TOTAL);
  const float NEG_INF = -__builtin_inff();

  const float x0v = xrow[c0];
  const float x1v = v1 ? xrow[c1] : NEG_INF;
  const float x2v = v2 ? xrow[c2] : NEG_INF;

  float vmax = fmaxf(x0v, fmaxf(x1v, x2v));
#pragma unroll
  for (int off = 32; off > 0; off >>= 1)
    vmax = fmaxf(vmax, __shfl_xor(vmax, off, 64));
  if (lane == 0) s_max[wid] = vmax;
  __syncthreads();
  const float m = fmaxf(fmaxf(s_max[0], s_max[1]), fmaxf(s_max[2], s_max[3]));

  const float e0 = expf(x0v - m);
  const float e1 = v1 ? expf(x1v - m) : 0.0f;
  const float e2 = v2 ? expf(x2v - m) : 0.0f;
  float vsum = e0 + e1 + e2;
#pragma unroll
  for (int off = 32; off > 0; off >>= 1)
    vsum += __shfl_xor(vsum, off, 64);
  if (lane == 0) s_sum[wid] = vsum;
  __syncthreads();
  const float sum = (s_sum[0] + s_sum[1]) + (s_sum[2] + s_sum[3]);

  const float lse = logf(sum);
  xrow[c0] = e0 / sum;
  if (v1) xrow[c1] = e1 / sum;
  if (v2) xrow[c2] = e2 / sum;

  const uint32_t base = (uint32_t)row * (uint32_t)N_TOTAL;
  float bv = jax_gumbel(base + c0) + ((x0v - m) - lse);
  int bi = c0;
  if (v1) {
    const float s1 = jax_gumbel(base + c1) + ((x1v - m) - lse);
    if (s1 > bv) { bv = s1; bi = c1; }
  }
  if (v2) {
    const float s2 = jax_gumbel(base + c2) + ((x2v - m) - lse);
    if (s2 > bv) { bv = s2; bi = c2; }
  }
#pragma unroll
  for (int off = 32; off > 0; off >>= 1) {
    const float ov = __shfl_xor(bv, off, 64);
    const int oi = __shfl_xor(bi, off, 64);
    if (ov > bv || (ov == bv && oi < bi)) { bv = ov; bi = oi; }
  }
  if (lane == 0) { s_av[wid] = bv; s_ai[wid] = bi; }
  __syncthreads();
  float best = s_av[0]; int action = s_ai[0];
#pragma unroll
  for (int w = 1; w < 4; ++w) {
    if (s_av[w] > best || (s_av[w] == best && s_ai[w] < action)) {
      best = s_av[w]; action = s_ai[w];
    }
  }

  const float* __restrict__ w2row = W2 + (size_t)action * D_TOTAL;
  const float* __restrict__ crow = core + (size_t)row * D_TOTAL;
  float* __restrict__ orow = out1 + (size_t)row * D_TOTAL;
#pragma unroll
  for (int d = t; d < D_TOTAL; d += 256) {
    const float h = w2row[d] + b2[d];
    orow[d] = fmaxf(h, 0.0f) + crow[d];
  }
}

// ---------------------------------------------------------------------------
extern "C" void kernel_launch(void* const* d_in, const int* in_sizes, int n_in,
                              void* d_out, int out_size, void* d_ws, size_t ws_size,
                              hipStream_t stream) {
  const float* core = (const float*)d_in[0];  // [16384,1024]
  const float* W1   = (const float*)d_in[1];  // [1024,572]
  const float* b1   = (const float*)d_in[2];  // [572]
  const float* W2   = (const float*)d_in[3];  // [572,1024]
  const float* b2   = (const float*)d_in[4];  // [1024]

  float* probs = (float*)d_out;                              // [16384,572]
  float* out1  = (float*)d_out + (size_t)M_TOTAL * N_TOTAL;  // [16384,1024]

  const size_t wneed = (size_t)2 * N_PAD * K_TOTAL * sizeof(f16);  // 2.6 MB
  if (ws_size >= wneed) {
    f16* wHi = (f16*)d_ws;
    f16* wLo = wHi + (size_t)N_PAD * K_TOTAL;
    convert_w<<<dim3(N_PAD / 32, K_TOTAL / 32), 256, 0, stream>>>(W1, wHi, wLo);
    gemm_frag<<<(M_TOTAL / BMF) * (N_PAD / BNF), 256, 0, stream>>>(core, wHi, wLo, b1, probs);
  } else {
    gemm_pre<<<dim3((N_TOTAL + 63) / 64, M_TOTAL / 64), 256, 0, stream>>>(core, W1, b1, probs);
  }

  head_kernel<<<M_TOTAL, 256, 0, stream>>>(probs, core, W2, b2, out1);
}